// Round 5
// baseline (369.822 us; speedup 1.0000x reference)
//
#include <hip/hip_runtime.h>
#include <hip/hip_bf16.h>
#include <cmath>

#define DEV __device__ __forceinline__

typedef __bf16 bf16x8 __attribute__((ext_vector_type(8)));
typedef float f32x4 __attribute__((ext_vector_type(4)));
typedef unsigned int u32;
typedef unsigned short u16;

#define S_VMCNT(N) asm volatile("s_waitcnt vmcnt(" #N ")" ::: "memory")
#define S_LGKM0    asm volatile("s_waitcnt lgkmcnt(0)" ::: "memory")
#define S_FENCE    asm volatile("" ::: "memory")
#define S_BAR      __builtin_amdgcn_s_barrier()

DEV u16 f2bf(float f) {
  union { float f; u32 u; } v;
  v.f = f;
  u32 u = v.u;
  u += 0x7fffu + ((u >> 16) & 1u);   // RNE
  return (u16)(u >> 16);
}
DEV u32 pk2(float a, float b) {
  union { __hip_bfloat162 h2; u32 u; } v;
  v.h2 = __float22bfloat162_rn(float2{a, b});
  return v.u;
}

DEV void async16(const void* g, void* l) {
  __builtin_amdgcn_global_load_lds((const __attribute__((address_space(1))) u32*)g,
                                   (__attribute__((address_space(3))) u32*)l, 16, 0, 0);
}

// XOR-swizzled tile-image offset (u16 units): 128 rows x 64 k bf16 per 16KB image.
DEV int swz(int row, int kq) { return row * 64 + ((kq * 8) ^ ((row & 7) << 3)); }

// ---------------------------------------------------------------------------
// fused QKV projection GEMM + (z==1) rank-expansion MLP tail.
// grid (128 row, 4 col, 3 tensor). Main loop = R2 structure (passing).
// z=0: q=elu+1 -> qact row-major. z=2: v -> vT[b][h][e][m].
// z=1: k=elu+1 kept in regs -> MLP with both heads in parallel (2 waves/head),
//      W1/W2 as register fragments from global (L2-hot), 6 barriers total.
// ---------------------------------------------------------------------------
__global__ __launch_bounds__(256, 2)
void qkv_gemm(const float* __restrict__ qin, const float* __restrict__ kin,
              const float* __restrict__ vin, const u16* __restrict__ WqP,
              const u16* __restrict__ WkP, const u16* __restrict__ WvP,
              const float* __restrict__ bq, const float* __restrict__ bk,
              const float* __restrict__ bv, const u16* __restrict__ W1T,
              const u16* __restrict__ W2T, const float* __restrict__ b1,
              const float* __restrict__ b2, u16* __restrict__ qact,
              u16* __restrict__ vT, u16* __restrict__ kaT, float invM)
{
  __shared__ __align__(16) u16 SB[32768];   // 64KB: main dbuf; MLP tail overlays

  const int z = blockIdx.z;
  const float* Af = z == 0 ? qin : z == 1 ? kin : vin;
  const u16* Bp = z == 0 ? WqP : z == 1 ? WkP : WvP;
  const float* bias = z == 0 ? bq : z == 1 ? bk : bv;

  const int tid = threadIdx.x, wv = tid >> 6, lane = tid & 63;
  const int wr = wv >> 1, wc = wv & 1;
  const int lrow = lane & 15, lq = lane >> 4;
  const long r0 = (long)blockIdx.x * 128;
  const int c0 = blockIdx.y * 128;

  f32x4 acc[4][4] = {};
  float4 rA[2][8];

  auto loadA = [&](float4* dst, int T) {
#pragma unroll
    for (int it = 0; it < 4; ++it) {
      const int s = it * 256 + tid;
      const int row = s >> 3, kq = s & 7;
      const float* g = Af + (r0 + row) * 512 + T * 64 + kq * 8;
      dst[2 * it]     = *(const float4*)g;
      dst[2 * it + 1] = *(const float4*)(g + 4);
    }
  };
  auto cvtStoreA = [&](const float4* src, u16* bufA) {
#pragma unroll
    for (int it = 0; it < 4; ++it) {
      const int s = it * 256 + tid;
      const int row = s >> 3, kq = s & 7;
      union { u32 q[4]; uint4 v; } pk;
      pk.q[0] = pk2(src[2 * it].x, src[2 * it].y);
      pk.q[1] = pk2(src[2 * it].z, src[2 * it].w);
      pk.q[2] = pk2(src[2 * it + 1].x, src[2 * it + 1].y);
      pk.q[3] = pk2(src[2 * it + 1].z, src[2 * it + 1].w);
      *(uint4*)&bufA[swz(row, kq)] = pk.v;
    }
  };
  auto issueB = [&](int T, u16* bufB) {
#pragma unroll
    for (int it = 0; it < 4; ++it) {
      const int sl = it * 256 + wv * 64;
      async16(Bp + ((long)blockIdx.y * 8 + T) * 8192 + (sl + lane) * 8, &bufB[sl * 8]);
    }
  };
  auto computeT = [&](const u16* Ac, const u16* Bc) {
#pragma unroll
    for (int subk = 0; subk < 2; ++subk) {
      bf16x8 af[4], bfr[4];
#pragma unroll
      for (int i = 0; i < 4; ++i)
        af[i] = *(const bf16x8*)&Ac[swz(wr * 64 + i * 16 + lrow, subk * 4 + lq)];
#pragma unroll
      for (int j = 0; j < 4; ++j)
        bfr[j] = *(const bf16x8*)&Bc[swz(wc * 64 + j * 16 + lrow, subk * 4 + lq)];
#pragma unroll
      for (int i = 0; i < 4; ++i)
#pragma unroll
        for (int j = 0; j < 4; ++j)
          acc[i][j] = __builtin_amdgcn_mfma_f32_16x16x32_bf16(af[i], bfr[j], acc[i][j], 0, 0, 0);
    }
  };

  // prologue: tile0 staged fully, tile1 A-regs in flight
  issueB(0, SB + 8192);
  S_FENCE;
  loadA(rA[0], 0);
  loadA(rA[1], 1);
  cvtStoreA(rA[0], SB);
  S_LGKM0;
  S_VMCNT(8);
  S_BAR;

#pragma unroll
  for (int t = 0; t < 8; ++t) {
    const int cur = t & 1, nxt = 1 - cur;
    u16* Ac = SB + cur * 16384;
    u16* Bc = Ac + 8192;
    u16* An = SB + nxt * 16384;
    u16* Bn = An + 8192;
    if (t < 7) issueB(t + 1, Bn);
    S_FENCE;
    if (t < 6) loadA(rA[cur], t + 2);
    if (t < 7) cvtStoreA(rA[nxt], An);
    computeT(Ac, Bc);
    S_LGKM0;
    if (t < 6)       { S_VMCNT(8); }
    else if (t == 6) { S_VMCNT(0); }
    S_BAR;
  }

  if (z == 0) {
    // elu+1, row-major bf16
#pragma unroll
    for (int i = 0; i < 4; ++i) {
#pragma unroll
      for (int j = 0; j < 4; ++j) {
        const int col = c0 + wc * 64 + j * 16 + lrow;
        const float bvv = bias[col];
#pragma unroll
        for (int p = 0; p < 4; ++p) {
          float o = acc[i][j][p] + bvv;
          o = (o > 0.f) ? (o + 1.f) : __expf(o);
          const long row = r0 + wr * 64 + i * 16 + lq * 4 + p;
          qact[row * 512 + col] = f2bf(o);
        }
      }
    }
  } else if (z == 2) {
    // identity -> vT[b][h][e][m] via per-wave LDS bounce (64e x 64m, pad 72)
    __syncthreads();
    u16* LTv = SB + wv * 4608;
#pragma unroll
    for (int i = 0; i < 4; ++i) {
#pragma unroll
      for (int j = 0; j < 4; ++j) {
        const int col = c0 + wc * 64 + j * 16 + lrow;
        const float bvv = bias[col];
        ushort4 w;
        w.x = f2bf(acc[i][j][0] + bvv);
        w.y = f2bf(acc[i][j][1] + bvv);
        w.z = f2bf(acc[i][j][2] + bvv);
        w.w = f2bf(acc[i][j][3] + bvv);
        *(ushort4*)&LTv[(j * 16 + lrow) * 72 + i * 16 + lq * 4] = w;
      }
    }
    const int b = (int)(r0 >> 12);
    const int h = (c0 + wc * 64) >> 6;
    const int mg0 = (int)(r0 & 4095) + wr * 64;
    __syncthreads();
#pragma unroll
    for (int ps = 0; ps < 8; ++ps) {
      const int e = ps * 8 + (lane >> 3);
      const int mq = (lane & 7) * 8;
      uint4 v = *(const uint4*)&LTv[e * 72 + mq];
      *(uint4*)(vT + (((long)b * 8 + h) * 64 + e) * 4096 + mg0 + mq) = v;
    }
  } else {
    // ---- fused MLP, both heads in parallel (2 waves per head) ----
    // kaT[bh][d][m] = (elu(gelu(k_act@W1+b1)@W2+b2)+1)/M
    // LDS overlays: As_k[2][128][72] (18432 u16) -> hid[2] swizzled [128][128]
    // (32768 u16) -> LT2[2][64][136] (17408 u16). 6 barriers total.
    u16* As_k = SB;
    u16* hid  = SB;
    u16* LT2  = SB;
    const int b   = (int)(r0 >> 12);
    const int m0g = (int)(r0 & 4095);
    const int h0  = c0 >> 6;
    const int hw  = wv & 1;          // this wave's head (== wc)
    const int mh  = (wv >> 1) * 64;  // this wave's m-half for GEMM phases
    __syncthreads();

    // scatter k_act (elu+1, bf16): wave (wr,wc) owns head wc, rows wr*64..+63
#pragma unroll
    for (int i = 0; i < 4; ++i)
#pragma unroll
      for (int j = 0; j < 4; ++j) {
        const int col = c0 + wc * 64 + j * 16 + lrow;
        const float bvv = bias[col];
        const int d = j * 16 + lrow;
        const int mb = wr * 64 + i * 16 + lq * 4;
#pragma unroll
        for (int p = 0; p < 4; ++p) {
          float o = acc[i][j][p] + bvv;
          o = (o > 0.f) ? (o + 1.f) : __expf(o);
          As_k[wc * 9216 + (mb + p) * 72 + d] = f2bf(o);
        }
      }
    __syncthreads();

    // GEMM1: hid_pre[c 0..128][m in half] for head hw; W1 frags from global
    f32x4 acc1[8][4] = {};
#pragma unroll
    for (int kt = 0; kt < 2; ++kt) {
      bf16x8 wa[8], kb[4];
#pragma unroll
      for (int i = 0; i < 8; ++i)
        wa[i] = *(const bf16x8*)(W1T + (i * 16 + lrow) * 64 + kt * 32 + lq * 8);
#pragma unroll
      for (int j = 0; j < 4; ++j)
        kb[j] = *(const bf16x8*)&As_k[hw * 9216 + (mh + j * 16 + lrow) * 72 + kt * 32 + lq * 8];
#pragma unroll
      for (int i = 0; i < 8; ++i)
#pragma unroll
        for (int j = 0; j < 4; ++j)
          acc1[i][j] = __builtin_amdgcn_mfma_f32_16x16x32_bf16(wa[i], kb[j], acc1[i][j], 0, 0, 0);
    }
    __syncthreads();   // As_k reads done before hid overlays

    // hid = gelu(pre + b1), XOR-swizzled [128m][128c] per head
#pragma unroll
    for (int i = 0; i < 8; ++i) {
      const int cc = i * 16 + lq * 4;
      float4 bv4 = *(const float4*)(b1 + cc);
#pragma unroll
      for (int j = 0; j < 4; ++j) {
        const int m = mh + j * 16 + lrow;
        float x0 = acc1[i][j][0] + bv4.x, x1 = acc1[i][j][1] + bv4.y;
        float x2 = acc1[i][j][2] + bv4.z, x3 = acc1[i][j][3] + bv4.w;
        ushort4 w;
        w.x = f2bf(0.5f * x0 * (1.f + erff(x0 * 0.7071067811865475f)));
        w.y = f2bf(0.5f * x1 * (1.f + erff(x1 * 0.7071067811865475f)));
        w.z = f2bf(0.5f * x2 * (1.f + erff(x2 * 0.7071067811865475f)));
        w.w = f2bf(0.5f * x3 * (1.f + erff(x3 * 0.7071067811865475f)));
        const int off = hw * 16384 + m * 128 + ((((cc >> 3) ^ (m & 7)) << 3) | (cc & 7));
        *(ushort4*)&hid[off] = w;
      }
    }
    __syncthreads();

    // GEMM2: out[m in half][d 0..64] for head hw; W2 frags from global
    f32x4 acc2[4][4] = {};
#pragma unroll
    for (int kt = 0; kt < 4; ++kt) {
      bf16x8 wa2[4], hb[4];
#pragma unroll
      for (int i = 0; i < 4; ++i)
        wa2[i] = *(const bf16x8*)(W2T + (i * 16 + lrow) * 128 + kt * 32 + lq * 8);
#pragma unroll
      for (int j = 0; j < 4; ++j) {
        const int m = mh + j * 16 + lrow;
        const int k0 = kt * 32 + lq * 8;
        hb[j] = *(const bf16x8*)&hid[hw * 16384 + m * 128 + (((k0 >> 3) ^ (m & 7)) << 3)];
      }
#pragma unroll
      for (int j = 0; j < 4; ++j)
#pragma unroll
        for (int i = 0; i < 4; ++i)
          acc2[j][i] = __builtin_amdgcn_mfma_f32_16x16x32_bf16(hb[j], wa2[i], acc2[j][i], 0, 0, 0);
    }
    __syncthreads();   // hid reads done before LT2 overlays

    // elu+1, /M -> LT2[head*64+d][136 m-pad]
#pragma unroll
    for (int i = 0; i < 4; ++i) {
      const int d = i * 16 + lrow;
      const float bd = b2[d];
#pragma unroll
      for (int j = 0; j < 4; ++j) {
        const int ml = mh + j * 16 + lq * 4;
        ushort4 w;
#pragma unroll
        for (int p = 0; p < 4; ++p) {
          float v = acc2[j][i][p] + bd;
          v = ((v > 0.f) ? (v + 1.f) : __expf(v)) * invM;
          ((u16*)&w)[p] = f2bf(v);
        }
        *(ushort4*)&LT2[(hw * 64 + d) * 136 + ml] = w;
      }
    }
    __syncthreads();

    // coalesced store: kaT[b*8+h0+head][d][m0g..+128]
#pragma unroll
    for (int it = 0; it < 8; ++it) {
      const int u = it * 256 + tid;
      const int mo = u & 15, hd = u >> 4;
      uint4 v = *(const uint4*)&LT2[hd * 136 + mo * 8];
      *(uint4*)(kaT + ((long)(b * 8 + h0 + (hd >> 6)) * 64 + (hd & 63)) * 4096 + m0g + mo * 8) = v;
    }
  }
}

// ---------------------------------------------------------------------------
// final projection: d_out[row][col] = attn(bf16) @ WoT + bo, fp32 out.
// ---------------------------------------------------------------------------
__global__ __launch_bounds__(256, 2)
void out_gemm(const u16* __restrict__ A, const u16* __restrict__ Bt,
              const float* __restrict__ bias, float* __restrict__ Y)
{
  __shared__ __align__(16) u16 SB[32768];
  const int tid = threadIdx.x, wv = tid >> 6, lane = tid & 63;
  const int wr = wv >> 1, wc = wv & 1;
  const int lrow = lane & 15, lq = lane >> 4;
  const long r0 = (long)blockIdx.x * 128;
  const int c0 = blockIdx.y * 128;

  auto stage = [&](int T, u16* buf) {
#pragma unroll
    for (int it = 0; it < 4; ++it) {
      const int sl = it * 256 + wv * 64;
      async16(A  + ((long)blockIdx.x * 8 + T) * 8192 + (sl + lane) * 8, &buf[sl * 8]);
      async16(Bt + ((long)blockIdx.y * 8 + T) * 8192 + (sl + lane) * 8, &buf[8192 + sl * 8]);
    }
  };

  f32x4 acc[4][4] = {};
  stage(0, SB);
  S_VMCNT(0);
  S_BAR;

#pragma unroll
  for (int t = 0; t < 8; ++t) {
    const int cur = t & 1, nxt = 1 - cur;
    if (t < 7) stage(t + 1, SB + nxt * 16384);
    const u16* Ac = SB + cur * 16384;
    const u16* Bc = Ac + 8192;
#pragma unroll
    for (int subk = 0; subk < 2; ++subk) {
      bf16x8 af[4], bfr[4];
#pragma unroll
      for (int i = 0; i < 4; ++i)
        af[i] = *(const bf16x8*)&Ac[swz(wr * 64 + i * 16 + lrow, subk * 4 + lq)];
#pragma unroll
      for (int j = 0; j < 4; ++j)
        bfr[j] = *(const bf16x8*)&Bc[swz(wc * 64 + j * 16 + lrow, subk * 4 + lq)];
#pragma unroll
      for (int i = 0; i < 4; ++i)
#pragma unroll
        for (int j = 0; j < 4; ++j)
          acc[i][j] = __builtin_amdgcn_mfma_f32_16x16x32_bf16(af[i], bfr[j], acc[i][j], 0, 0, 0);
    }
    S_LGKM0;
    if (t < 7) { S_VMCNT(0); }
    S_BAR;
  }
#pragma unroll
  for (int i = 0; i < 4; ++i) {
#pragma unroll
    for (int j = 0; j < 4; ++j) {
      const int col = c0 + wc * 64 + j * 16 + lrow;
      const float bv = bias[col];
#pragma unroll
      for (int p = 0; p < 4; ++p) {
        const long row = r0 + wr * 64 + i * 16 + lq * 4 + p;
        Y[row * 512 + col] = acc[i][j][p] + bv;
      }
    }
  }
}

// ---------------------------------------------------------------------------
// weight transpose+convert: W [K,N] fp32 -> blocked swizzled bf16 images for
// the 512x512 GEMM weights (m<4); row-major [N,K] bf16 for W1/W2.
// ---------------------------------------------------------------------------
struct TArgs {
  const float* src[6];
  u16* dst[6];
  int K[6];
  int N[6];
};
__global__ __launch_bounds__(256)
void transpose_w(TArgs a)
{
  const int m = blockIdx.z;
  const int K = a.K[m], N = a.N[m];
  const int kt = blockIdx.y * 64, nt = blockIdx.x * 64;
  if (kt >= K || nt >= N) return;
  const float* src = a.src[m];
  u16* dst = a.dst[m];
  __shared__ u16 t[64][72];
  const int tx = threadIdx.x & 15, ty = threadIdx.x >> 4;
#pragma unroll
  for (int rr = 0; rr < 64; rr += 16) {
    const int k = kt + ty + rr;
    float4 v = *(const float4*)(src + (long)k * N + nt + tx * 4);
    t[tx * 4 + 0][ty + rr] = f2bf(v.x);
    t[tx * 4 + 1][ty + rr] = f2bf(v.y);
    t[tx * 4 + 2][ty + rr] = f2bf(v.z);
    t[tx * 4 + 3][ty + rr] = f2bf(v.w);
  }
  __syncthreads();
  if (m < 4) {
    const int ktile = kt >> 6;
#pragma unroll
    for (int it = 0; it < 2; ++it) {
      const int s = threadIdx.x + it * 256;
      const int r = s >> 3, c = (s & 7) * 8;
      const int n = nt + r;
      const int colblk = n >> 7, cl = n & 127;
      ushort4 u0 = *(ushort4*)&t[r][c];
      ushort4 u1 = *(ushort4*)&t[r][c + 4];
      u16* d = dst + ((long)colblk * 8 + ktile) * 8192 + cl * 64 + (c ^ ((cl & 7) << 3));
      *(ushort4*)d = u0;
      *(ushort4*)(d + 4) = u1;
    }
  } else {
#pragma unroll
    for (int it = 0; it < 2; ++it) {
      const int s = threadIdx.x + it * 256;
      const int r = s >> 3, c = (s & 7) * 8;
      ushort4 u0 = *(ushort4*)&t[r][c];
      ushort4 u1 = *(ushort4*)&t[r][c + 4];
      *(ushort4*)(dst + (long)(nt + r) * K + kt + c) = u0;
      *(ushort4*)(dst + (long)(nt + r) * K + kt + c + 4) = u1;
    }
  }
}

// ---------------------------------------------------------------------------
// kv GEMM: D[d][e] = sum_m kaT*vT, split-K 16, + ksum via ones.
// ---------------------------------------------------------------------------
__global__ __launch_bounds__(256, 2)
void kv_gemm(const u16* __restrict__ kaT, const u16* __restrict__ vT,
             float* __restrict__ kvp, float* __restrict__ ksp)
{
  const int sp = blockIdx.x;
  const int bh = blockIdx.y;
  __shared__ __align__(16) u16 SB[32768];
  const int tid = threadIdx.x, wv = tid >> 6, lane = tid & 63;
  const int lrow = lane & 15, lq = lane >> 4;
  f32x4 acc[4][4] = {};
  f32x4 accs[4] = {};
  bf16x8 ones;
#pragma unroll
  for (int z = 0; z < 8; ++z) ones[z] = (__bf16)1.0f;
  const long base = (long)bh * 64 * 4096;

#pragma unroll
  for (int ph = 0; ph < 2; ++ph) {
    const int m0 = sp * 256 + ph * 128;
#pragma unroll
    for (int i = 0; i < 4; ++i) {
      const int s = (wv * 4 + i) * 64 + lane;
      const int chunk = s >> 8, row = (s >> 2) & 63, part = s & 3;
      const long g = base + (long)row * 4096 + m0 + chunk * 32 + part * 8;
      async16(kaT + g, &SB[ph * 16384 + (wv * 4 + i) * 512]);
      async16(vT + g, &SB[ph * 16384 + 8192 + (wv * 4 + i) * 512]);
    }
    S_FENCE;
  }

#pragma unroll
  for (int ph = 0; ph < 2; ++ph) {
    if (ph == 0) { S_VMCNT(8); } else { S_VMCNT(0); }
    const u16* As = SB + ph * 16384;
    const u16* Bs = As + 8192;
    bf16x8 af[4], bfr[4];
#pragma unroll
    for (int i = 0; i < 4; ++i)
      af[i] = *(const bf16x8*)&As[wv * 2048 + (i * 16 + lrow) * 32 + lq * 8];
#pragma unroll
    for (int j = 0; j < 4; ++j)
      bfr[j] = *(const bf16x8*)&Bs[wv * 2048 + (j * 16 + lrow) * 32 + lq * 8];
#pragma unroll
    for (int i = 0; i < 4; ++i) {
#pragma unroll
      for (int j = 0; j < 4; ++j)
        acc[i][j] = __builtin_amdgcn_mfma_f32_16x16x32_bf16(af[i], bfr[j], acc[i][j], 0, 0, 0);
      accs[i] = __builtin_amdgcn_mfma_f32_16x16x32_bf16(af[i], ones, accs[i], 0, 0, 0);
    }
  }

  float* red = (float*)SB;
  float* ksr = red + 64 * 68;
  for (int w = 0; w < 4; ++w) {
    __syncthreads();
    if (wv == w) {
#pragma unroll
      for (int i = 0; i < 4; ++i) {
#pragma unroll
        for (int j = 0; j < 4; ++j) {
          const int e = j * 16 + lrow, dd = i * 16 + lq * 4;
          float* p = &red[e * 68 + dd];
          if (w == 0) { p[0] = acc[i][j][0]; p[1] = acc[i][j][1]; p[2] = acc[i][j][2]; p[3] = acc[i][j][3]; }
          else        { p[0] += acc[i][j][0]; p[1] += acc[i][j][1]; p[2] += acc[i][j][2]; p[3] += acc[i][j][3]; }
        }
        if (lrow == 0) {
          const int dd = i * 16 + lq * 4;
#pragma unroll
          for (int p2 = 0; p2 < 4; ++p2) {
            if (w == 0) ksr[dd + p2] = accs[i][p2];
            else        ksr[dd + p2] += accs[i][p2];
          }
        }
      }
    }
  }
  __syncthreads();
  float* kvo = kvp + ((long)sp * 32 + bh) * 4096;
  for (int s = tid; s < 4096; s += 256) kvo[s] = red[(s >> 6) * 68 + (s & 63)];
  if (tid < 64) ksp[(sp * 32 + bh) * 64 + tid] = ksr[tid];
}

__global__ __launch_bounds__(256)
void kv_reduce(const float* __restrict__ kvp, const float* __restrict__ ksp,
               u16* __restrict__ kvT, u16* __restrict__ ksumT)
{
  const int bh = blockIdx.x;
  const int t = threadIdx.x;
  const int s0 = blockIdx.y * 512;
#pragma unroll
  for (int i = 0; i < 2; ++i) {
    const int s = s0 + i * 256 + t;
    float v = 0.f;
#pragma unroll
    for (int sp = 0; sp < 16; ++sp) v += kvp[((long)sp * 32 + bh) * 4096 + s];
    kvT[(long)bh * 4096 + s] = f2bf(v);
  }
  if (blockIdx.y == 0 && t < 64) {
    float v = 0.f;
#pragma unroll
    for (int sp = 0; sp < 16; ++sp) v += ksp[(sp * 32 + bh) * 64 + t];
    ksumT[bh * 64 + t] = f2bf(v);
  }
}

// ---------------------------------------------------------------------------
// attn MFMA: out[n][e] = (q@kv) / max(q@ksum,1e-6).
// Output written as blocked swizzled images for out_gemm.
// ---------------------------------------------------------------------------
__global__ __launch_bounds__(256)
void attn_mfma(const u16* __restrict__ q, const u16* __restrict__ kvT,
               const u16* __restrict__ ksumT, u16* __restrict__ attn)
{
  __shared__ u16 SB[17408];
  const int tid = threadIdx.x, wv = tid >> 6, lane = tid & 63;
  const int lrow = lane & 15, lq = lane >> 4;
  const int n0 = blockIdx.x * 256;
  const int bh = blockIdx.y, b = bh >> 3, h = bh & 7;
  u16* As = SB;

#pragma unroll
  for (int half = 0; half < 2; ++half)
#pragma unroll
    for (int i = 0; i < 4; ++i) {
      const int s = (wv * 4 + i) * 64 + lane;
      async16(q + ((long)(b * 4096 + n0 + (s >> 2))) * 512 + h * 64 + half * 32 + (s & 3) * 8,
              &As[half * 8192 + (wv * 4 + i) * 512]);
    }
  bf16x8 bfr[2][4], ks[2];
#pragma unroll
  for (int half = 0; half < 2; ++half) {
#pragma unroll
    for (int j = 0; j < 4; ++j)
      bfr[half][j] = *(const bf16x8*)(kvT + ((long)bh * 64 + j * 16 + lrow) * 64 + half * 32 + lq * 8);
    ks[half] = *(const bf16x8*)(ksumT + bh * 64 + half * 32 + lq * 8);
  }
  __syncthreads();

  f32x4 acc[4][4] = {};
  f32x4 accd[4] = {};
#pragma unroll
  for (int half = 0; half < 2; ++half) {
    bf16x8 af[4];
#pragma unroll
    for (int i = 0; i < 4; ++i)
      af[i] = *(const bf16x8*)&As[half * 8192 + (wv * 64 + i * 16 + lrow) * 32 + lq * 8];
#pragma unroll
    for (int i = 0; i < 4; ++i) {
#pragma unroll
      for (int j = 0; j < 4; ++j)
        acc[i][j] = __builtin_amdgcn_mfma_f32_16x16x32_bf16(af[i], bfr[half][j], acc[i][j], 0, 0, 0);
      accd[i] = __builtin_amdgcn_mfma_f32_16x16x32_bf16(af[i], ks[half], accd[i], 0, 0, 0);
    }
  }
  __syncthreads();

  u16* LT = SB;
#pragma unroll
  for (int i = 0; i < 4; ++i) {
    float dinv[4];
#pragma unroll
    for (int p = 0; p < 4; ++p) dinv[p] = 1.f / fmaxf(accd[i][p], 1e-6f);
#pragma unroll
    for (int j = 0; j < 4; ++j) {
      const int e = j * 16 + lrow;
      const int nl0 = i * 16 + lq * 4;
      ushort4 w;
      float x0 = acc[i][j][0] * dinv[0], x1 = acc[i][j][1] * dinv[1];
      float x2 = acc[i][j][2] * dinv[2], x3 = acc[i][j][3] * dinv[3];
      if (!(x0 == x0)) x0 = 0.f;
      if (!(x1 == x1)) x1 = 0.f;
      if (!(x2 == x2)) x2 = 0.f;
      if (!(x3 == x3)) x3 = 0.f;
      w.x = f2bf(fminf(65000.f, fmaxf(-65000.f, x0)));
      w.y = f2bf(fminf(65000.f, fmaxf(-65000.f, x1)));
      w.z = f2bf(fminf(65000.f, fmaxf(-65000.f, x2)));
      w.w = f2bf(fminf(65000.f, fmaxf(-65000.f, x3)));
      *(ushort4*)&LT[wv * 4352 + e * 68 + nl0] = w;
    }
  }
  __syncthreads();
#pragma unroll
  for (int it = 0; it < 8; ++it) {
    const int c = it * 256 + tid;
    const int n = c & 255, ec = c >> 8;
    const int wr2 = n >> 6, nl = n & 63;
    ushort4 w0, w1;
    w0.x = LT[wr2 * 4352 + (ec * 8 + 0) * 68 + nl];
    w0.y = LT[wr2 * 4352 + (ec * 8 + 1) * 68 + nl];
    w0.z = LT[wr2 * 4352 + (ec * 8 + 2) * 68 + nl];
    w0.w = LT[wr2 * 4352 + (ec * 8 + 3) * 68 + nl];
    w1.x = LT[wr2 * 4352 + (ec * 8 + 4) * 68 + nl];
    w1.y = LT[wr2 * 4352 + (ec * 8 + 5) * 68 + nl];
    w1.z = LT[wr2 * 4352 + (ec * 8 + 6) * 68 + nl];
    w1.w = LT[wr2 * 4352 + (ec * 8 + 7) * 68 + nl];
    const int ng = b * 4096 + n0 + n;
    const int rowblk = ng >> 7, rl = ng & 127;
    u16* dst = attn + ((long)rowblk * 8 + h) * 8192 + rl * 64 + ((ec * 8) ^ ((rl & 7) << 3));
    *(ushort4*)dst = w0;
    *(ushort4*)(dst + 4) = w1;
  }
}

// ---------------------------------------------------------------------------
static constexpr long U = 8388608;   // elems of one [4,4096,512] tensor

extern "C" void kernel_launch(void* const* d_in, const int* in_sizes, int n_in,
                              void* d_out, int out_size, void* d_ws, size_t ws_size,
                              hipStream_t stream)
{
  const float* query = (const float*)d_in[0];
  const float* key   = (const float*)d_in[1];
  const float* value = (const float*)d_in[2];
  const float* Wq = (const float*)d_in[3];
  const float* bq = (const float*)d_in[4];
  const float* Wk = (const float*)d_in[5];
  const float* bk = (const float*)d_in[6];
  const float* Wv = (const float*)d_in[7];
  const float* bv = (const float*)d_in[8];
  const float* W1 = (const float*)d_in[9];
  const float* b1 = (const float*)d_in[10];
  const float* W2 = (const float*)d_in[11];
  const float* b2 = (const float*)d_in[12];
  const float* Wo = (const float*)d_in[13];
  const float* bo = (const float*)d_in[14];

  u16* wsh = (u16*)d_ws;
  u16* qact = wsh;           // [16384,512] bf16
  u16* vT   = wsh + 2 * U;   // vT[b][h][e][m]
  u16* kaT  = wsh + 3 * U;   // [32][64][4096]
  u16* attn = wsh + 4 * U;   // blocked swizzled [128 rowblk][8 ktile][8192]

  float* fp  = (float*)(wsh + 5 * U);
  float* kvp = fp;                     // 16*32*4096
  float* ksp = fp + 2097152;           // 16*32*64
  u16* kvTg   = (u16*)(fp + 2129920);  // 32*4096
  u16* ksumTg = kvTg + 131072;         // 32*64
  u16* wtb = ksumTg + 2048;
  u16* WqT = wtb;                      // blocked [4][8][8192]
  u16* WkT = wtb + 262144;
  u16* WvT = wtb + 524288;
  u16* WoT = wtb + 786432;
  u16* W1T = wtb + 1048576;            // [128,64] row-major
  u16* W2T = wtb + 1056768;            // [64,128] row-major

  dim3 blk(256);
  const float invM = 1.f / 4096.f;

  TArgs ta;
  ta.src[0] = Wq; ta.dst[0] = WqT; ta.K[0] = 512; ta.N[0] = 512;
  ta.src[1] = Wk; ta.dst[1] = WkT; ta.K[1] = 512; ta.N[1] = 512;
  ta.src[2] = Wv; ta.dst[2] = WvT; ta.K[2] = 512; ta.N[2] = 512;
  ta.src[3] = Wo; ta.dst[3] = WoT; ta.K[3] = 512; ta.N[3] = 512;
  ta.src[4] = W1; ta.dst[4] = W1T; ta.K[4] = 64;  ta.N[4] = 128;
  ta.src[5] = W2; ta.dst[5] = W2T; ta.K[5] = 128; ta.N[5] = 64;
  transpose_w<<<dim3(8, 8, 6), blk, 0, stream>>>(ta);

  // fused q/k/v projections + per-head MLP on the k path (writes kaT directly)
  qkv_gemm<<<dim3(128, 4, 3), blk, 0, stream>>>(query, key, value, WqT, WkT, WvT,
                                                bq, bk, bv, W1T, W2T, b1, b2,
                                                qact, vT, kaT, invM);
  // kv context + ksum (MFMA split-K 16) then reduce to bf16
  kv_gemm<<<dim3(16, 32), blk, 0, stream>>>(kaT, vT, kvp, ksp);
  kv_reduce<<<dim3(32, 8), blk, 0, stream>>>(kvp, ksp, kvTg, ksumTg);
  // attention output (blocked swizzled layout for out_gemm)
  attn_mfma<<<dim3(16, 32), blk, 0, stream>>>(qact, kvTg, ksumTg, attn);
  // final projection -> d_out fp32
  out_gemm<<<dim3(128, 4), blk, 0, stream>>>(attn, WoT, bo, (float*)d_out);
}

// Round 6
// 249.338 us; speedup vs baseline: 1.4832x; 1.4832x over previous
//
#include <hip/hip_runtime.h>
#include <hip/hip_bf16.h>
#include <cmath>

#define DEV __device__ __forceinline__

typedef __bf16 bf16x8 __attribute__((ext_vector_type(8)));
typedef float f32x4 __attribute__((ext_vector_type(4)));
typedef unsigned int u32;
typedef unsigned short u16;

#define S_VMCNT(N) asm volatile("s_waitcnt vmcnt(" #N ")" ::: "memory")
#define S_LGKM0    asm volatile("s_waitcnt lgkmcnt(0)" ::: "memory")
#define S_FENCE    asm volatile("" ::: "memory")
#define S_BAR      __builtin_amdgcn_s_barrier()

DEV u16 f2bf(float f) {
  union { float f; u32 u; } v;
  v.f = f;
  u32 u = v.u;
  u += 0x7fffu + ((u >> 16) & 1u);   // RNE
  return (u16)(u >> 16);
}
DEV u32 pk2(float a, float b) {
  union { __hip_bfloat162 h2; u32 u; } v;
  v.h2 = __float22bfloat162_rn(float2{a, b});
  return v.u;
}

DEV void async16(const void* g, void* l) {
  __builtin_amdgcn_global_load_lds((const __attribute__((address_space(1))) u32*)g,
                                   (__attribute__((address_space(3))) u32*)l, 16, 0, 0);
}

// XOR-swizzled tile-image offset (u16 units): 128 rows x 64 k bf16 per 16KB image.
DEV int swz(int row, int kq) { return row * 64 + ((kq * 8) ^ ((row & 7) << 3)); }

// ---------------------------------------------------------------------------
// fused QKV projection GEMM + (z==1) rank-expansion MLP tail.
// grid (128 row, 4 col, 3 tensor). Main loop = R2 structure (passing).
// z=0: q=elu+1 -> qact row-major. z=2: v -> vT[b][h][e][m].
// z=1: MLP tail, spill-free: scatter BOTH heads (acc dies), then per head
//      GEMM1 acc1[4][4] / GEMM2 acc2[4][2] with W1/W2 frags from global
//      (L2-broadcast, 16/32KB), all LDS XOR-swizzled, 6 barriers.
// ---------------------------------------------------------------------------
__global__ __launch_bounds__(256, 2)
void qkv_gemm(const float* __restrict__ qin, const float* __restrict__ kin,
              const float* __restrict__ vin, const u16* __restrict__ WqP,
              const u16* __restrict__ WkP, const u16* __restrict__ WvP,
              const float* __restrict__ bq, const float* __restrict__ bk,
              const float* __restrict__ bv, const u16* __restrict__ W1T,
              const u16* __restrict__ W2T, const float* __restrict__ b1,
              const float* __restrict__ b2, u16* __restrict__ qact,
              u16* __restrict__ vT, u16* __restrict__ kaT, float invM)
{
  __shared__ __align__(16) u16 SB[32768];   // 64KB: main dbuf; MLP tail overlays

  const int z = blockIdx.z;
  const float* Af = z == 0 ? qin : z == 1 ? kin : vin;
  const u16* Bp = z == 0 ? WqP : z == 1 ? WkP : WvP;
  const float* bias = z == 0 ? bq : z == 1 ? bk : bv;

  const int tid = threadIdx.x, wv = tid >> 6, lane = tid & 63;
  const int wr = wv >> 1, wc = wv & 1;
  const int lrow = lane & 15, lq = lane >> 4;
  const long r0 = (long)blockIdx.x * 128;
  const int c0 = blockIdx.y * 128;

  f32x4 acc[4][4] = {};
  float4 rA[2][8];

  auto loadA = [&](float4* dst, int T) {
#pragma unroll
    for (int it = 0; it < 4; ++it) {
      const int s = it * 256 + tid;
      const int row = s >> 3, kq = s & 7;
      const float* g = Af + (r0 + row) * 512 + T * 64 + kq * 8;
      dst[2 * it]     = *(const float4*)g;
      dst[2 * it + 1] = *(const float4*)(g + 4);
    }
  };
  auto cvtStoreA = [&](const float4* src, u16* bufA) {
#pragma unroll
    for (int it = 0; it < 4; ++it) {
      const int s = it * 256 + tid;
      const int row = s >> 3, kq = s & 7;
      union { u32 q[4]; uint4 v; } pk;
      pk.q[0] = pk2(src[2 * it].x, src[2 * it].y);
      pk.q[1] = pk2(src[2 * it].z, src[2 * it].w);
      pk.q[2] = pk2(src[2 * it + 1].x, src[2 * it + 1].y);
      pk.q[3] = pk2(src[2 * it + 1].z, src[2 * it + 1].w);
      *(uint4*)&bufA[swz(row, kq)] = pk.v;
    }
  };
  auto issueB = [&](int T, u16* bufB) {
#pragma unroll
    for (int it = 0; it < 4; ++it) {
      const int sl = it * 256 + wv * 64;
      async16(Bp + ((long)blockIdx.y * 8 + T) * 8192 + (sl + lane) * 8, &bufB[sl * 8]);
    }
  };
  auto computeT = [&](const u16* Ac, const u16* Bc) {
#pragma unroll
    for (int subk = 0; subk < 2; ++subk) {
      bf16x8 af[4], bfr[4];
#pragma unroll
      for (int i = 0; i < 4; ++i)
        af[i] = *(const bf16x8*)&Ac[swz(wr * 64 + i * 16 + lrow, subk * 4 + lq)];
#pragma unroll
      for (int j = 0; j < 4; ++j)
        bfr[j] = *(const bf16x8*)&Bc[swz(wc * 64 + j * 16 + lrow, subk * 4 + lq)];
#pragma unroll
      for (int i = 0; i < 4; ++i)
#pragma unroll
        for (int j = 0; j < 4; ++j)
          acc[i][j] = __builtin_amdgcn_mfma_f32_16x16x32_bf16(af[i], bfr[j], acc[i][j], 0, 0, 0);
    }
  };

  // prologue: tile0 staged fully, tile1 A-regs in flight
  issueB(0, SB + 8192);
  S_FENCE;
  loadA(rA[0], 0);
  loadA(rA[1], 1);
  cvtStoreA(rA[0], SB);
  S_LGKM0;
  S_VMCNT(8);
  S_BAR;

#pragma unroll
  for (int t = 0; t < 8; ++t) {
    const int cur = t & 1, nxt = 1 - cur;
    u16* Ac = SB + cur * 16384;
    u16* Bc = Ac + 8192;
    u16* An = SB + nxt * 16384;
    u16* Bn = An + 8192;
    if (t < 7) issueB(t + 1, Bn);
    S_FENCE;
    if (t < 6) loadA(rA[cur], t + 2);
    if (t < 7) cvtStoreA(rA[nxt], An);
    computeT(Ac, Bc);
    S_LGKM0;
    if (t < 6)       { S_VMCNT(8); }
    else if (t == 6) { S_VMCNT(0); }
    S_BAR;
  }

  if (z == 0) {
    // elu+1, row-major bf16
#pragma unroll
    for (int i = 0; i < 4; ++i) {
#pragma unroll
      for (int j = 0; j < 4; ++j) {
        const int col = c0 + wc * 64 + j * 16 + lrow;
        const float bvv = bias[col];
#pragma unroll
        for (int p = 0; p < 4; ++p) {
          float o = acc[i][j][p] + bvv;
          o = (o > 0.f) ? (o + 1.f) : __expf(o);
          const long row = r0 + wr * 64 + i * 16 + lq * 4 + p;
          qact[row * 512 + col] = f2bf(o);
        }
      }
    }
  } else if (z == 2) {
    // identity -> vT[b][h][e][m] via per-wave LDS bounce (64e x 64m, pad 72)
    u16* LTv = SB + wv * 4608;
#pragma unroll
    for (int i = 0; i < 4; ++i) {
#pragma unroll
      for (int j = 0; j < 4; ++j) {
        const int col = c0 + wc * 64 + j * 16 + lrow;
        const float bvv = bias[col];
        ushort4 w;
        w.x = f2bf(acc[i][j][0] + bvv);
        w.y = f2bf(acc[i][j][1] + bvv);
        w.z = f2bf(acc[i][j][2] + bvv);
        w.w = f2bf(acc[i][j][3] + bvv);
        *(ushort4*)&LTv[(j * 16 + lrow) * 72 + i * 16 + lq * 4] = w;
      }
    }
    const int b = (int)(r0 >> 12);
    const int h = (c0 + wc * 64) >> 6;
    const int mg0 = (int)(r0 & 4095) + wr * 64;
    __syncthreads();
#pragma unroll
    for (int ps = 0; ps < 8; ++ps) {
      const int e = ps * 8 + (lane >> 3);
      const int mq = (lane & 7) * 8;
      uint4 v = *(const uint4*)&LTv[e * 72 + mq];
      *(uint4*)(vT + (((long)b * 8 + h) * 64 + e) * 4096 + mg0 + mq) = v;
    }
  } else {
    // ---- fused MLP tail, spill-free ----
    // LDS: As_k[2 head][128 m][64 d swz] = 16384 u16 @0
    //      hid[128 m][128 c swz]         = 16384 u16 @16384
    //      LT2[64 d][128 m swz]          =  8192 u16 @hh*8192 (over As_k[hh])
    u16* As_k = SB;
    u16* hid  = SB + 16384;
    const int b   = (int)(r0 >> 12);
    const int m0g = (int)(r0 & 4095);
    const int h0  = c0 >> 6;

    // scatter BOTH heads' k_act (elu+1, bf16); wave (wr,wc): head wc, rows wr*64..
    // acc is fully consumed here -> dead for the rest of the kernel.
#pragma unroll
    for (int i = 0; i < 4; ++i)
#pragma unroll
      for (int j = 0; j < 4; ++j) {
        const int col = c0 + wc * 64 + j * 16 + lrow;
        const float bvv = bias[col];
        const int d = j * 16 + lrow;
#pragma unroll
        for (int p = 0; p < 4; ++p) {
          const int m = wr * 64 + i * 16 + lq * 4 + p;
          float o = acc[i][j][p] + bvv;
          o = (o > 0.f) ? (o + 1.f) : __expf(o);
          As_k[wc * 8192 + m * 64 + ((((d >> 3) ^ (m & 7)) << 3) | (d & 7))] = f2bf(o);
        }
      }
    __syncthreads();

    const int c0m = (wv >> 1) * 64, mh0 = (wv & 1) * 64;   // GEMM1 split
    const int d0  = (wv >> 1) * 32, mh2 = (wv & 1) * 64;   // GEMM2 split

    for (int hh = 0; hh < 2; ++hh) {
      // GEMM1: hid_pre[c][m] = sum_d W1[c][d]*k[m][d]; W1 frags from global
      f32x4 acc1[4][4] = {};
#pragma unroll
      for (int kt = 0; kt < 2; ++kt) {
        bf16x8 wa[4], kb[4];
#pragma unroll
        for (int i = 0; i < 4; ++i)
          wa[i] = *(const bf16x8*)(W1T + (c0m + i * 16 + lrow) * 64 + kt * 32 + lq * 8);
#pragma unroll
        for (int j = 0; j < 4; ++j) {
          const int m = mh0 + j * 16 + lrow;
          kb[j] = *(const bf16x8*)&As_k[hh * 8192 + m * 64 + (((kt * 4 + lq) ^ (m & 7)) << 3)];
        }
#pragma unroll
        for (int i = 0; i < 4; ++i)
#pragma unroll
          for (int j = 0; j < 4; ++j)
            acc1[i][j] = __builtin_amdgcn_mfma_f32_16x16x32_bf16(wa[i], kb[j], acc1[i][j], 0, 0, 0);
      }

      // hid = gelu(pre + b1), swizzled (hid region disjoint from As_k -> no bar)
#pragma unroll
      for (int i = 0; i < 4; ++i) {
        const int cc = c0m + i * 16 + lq * 4;
        float4 bv4 = *(const float4*)(b1 + cc);
#pragma unroll
        for (int j = 0; j < 4; ++j) {
          const int m = mh0 + j * 16 + lrow;
          float x0 = acc1[i][j][0] + bv4.x, x1 = acc1[i][j][1] + bv4.y;
          float x2 = acc1[i][j][2] + bv4.z, x3 = acc1[i][j][3] + bv4.w;
          ushort4 w;
          w.x = f2bf(0.5f * x0 * (1.f + erff(x0 * 0.7071067811865475f)));
          w.y = f2bf(0.5f * x1 * (1.f + erff(x1 * 0.7071067811865475f)));
          w.z = f2bf(0.5f * x2 * (1.f + erff(x2 * 0.7071067811865475f)));
          w.w = f2bf(0.5f * x3 * (1.f + erff(x3 * 0.7071067811865475f)));
          *(ushort4*)&hid[m * 128 + ((((cc >> 3) ^ (m & 7)) << 3) | (cc & 7))] = w;
        }
      }
      __syncthreads();   // hid ready; all As_k[hh] reads complete

      // GEMM2: out[m][d] = sum_c hid[m][c]*W2[d][c]; W2 frags from global
      f32x4 acc2[4][2] = {};
#pragma unroll
      for (int kt = 0; kt < 4; ++kt) {
        bf16x8 wa2[2], hb[4];
#pragma unroll
        for (int i = 0; i < 2; ++i)
          wa2[i] = *(const bf16x8*)(W2T + (d0 + i * 16 + lrow) * 128 + kt * 32 + lq * 8);
#pragma unroll
        for (int j = 0; j < 4; ++j) {
          const int m = mh2 + j * 16 + lrow;
          hb[j] = *(const bf16x8*)&hid[m * 128 + (((kt * 4 + lq) ^ (m & 7)) << 3)];
        }
#pragma unroll
        for (int j = 0; j < 4; ++j)
#pragma unroll
          for (int i = 0; i < 2; ++i)
            acc2[j][i] = __builtin_amdgcn_mfma_f32_16x16x32_bf16(hb[j], wa2[i], acc2[j][i], 0, 0, 0);
      }

      // elu+1, /M -> LT2[d][m] swizzled, overlaying As_k[hh] (reads done)
      u16* LT2 = SB + hh * 8192;
#pragma unroll
      for (int i = 0; i < 2; ++i) {
        const int d = d0 + i * 16 + lrow;
        const float bd = b2[d];
#pragma unroll
        for (int j = 0; j < 4; ++j) {
          const int ml = mh2 + j * 16 + lq * 4;
          ushort4 w;
#pragma unroll
          for (int p = 0; p < 4; ++p) {
            float v = acc2[j][i][p] + bd;
            v = ((v > 0.f) ? (v + 1.f) : __expf(v)) * invM;
            ((u16*)&w)[p] = f2bf(v);
          }
          *(ushort4*)&LT2[d * 128 + ((((ml >> 3) ^ (d & 7)) << 3) | (ml & 7))] = w;
        }
      }
      __syncthreads();   // LT2 ready

      // coalesced store: kaT[b*8+h0+hh][d][m0g..+128]
      const int bh2 = b * 8 + h0 + hh;
#pragma unroll
      for (int it = 0; it < 4; ++it) {
        const int u = it * 256 + tid;
        const int mo = u & 15, hd = u >> 4;
        uint4 v = *(const uint4*)&LT2[hd * 128 + ((mo ^ (hd & 7)) << 3)];
        *(uint4*)(kaT + ((long)bh2 * 64 + hd) * 4096 + m0g + mo * 8) = v;
      }
      // no barrier needed: hh=1 writes (hid, LT2@8192) are disjoint from
      // the regions hh=0's stores read (LT2@0), and hid readers are done.
    }
  }
}

// ---------------------------------------------------------------------------
// final projection: d_out[row][col] = attn(bf16) @ WoT + bo, fp32 out.
// ---------------------------------------------------------------------------
__global__ __launch_bounds__(256, 2)
void out_gemm(const u16* __restrict__ A, const u16* __restrict__ Bt,
              const float* __restrict__ bias, float* __restrict__ Y)
{
  __shared__ __align__(16) u16 SB[32768];
  const int tid = threadIdx.x, wv = tid >> 6, lane = tid & 63;
  const int wr = wv >> 1, wc = wv & 1;
  const int lrow = lane & 15, lq = lane >> 4;
  const long r0 = (long)blockIdx.x * 128;
  const int c0 = blockIdx.y * 128;

  auto stage = [&](int T, u16* buf) {
#pragma unroll
    for (int it = 0; it < 4; ++it) {
      const int sl = it * 256 + wv * 64;
      async16(A  + ((long)blockIdx.x * 8 + T) * 8192 + (sl + lane) * 8, &buf[sl * 8]);
      async16(Bt + ((long)blockIdx.y * 8 + T) * 8192 + (sl + lane) * 8, &buf[8192 + sl * 8]);
    }
  };

  f32x4 acc[4][4] = {};
  stage(0, SB);
  S_VMCNT(0);
  S_BAR;

#pragma unroll
  for (int t = 0; t < 8; ++t) {
    const int cur = t & 1, nxt = 1 - cur;
    if (t < 7) stage(t + 1, SB + nxt * 16384);
    const u16* Ac = SB + cur * 16384;
    const u16* Bc = Ac + 8192;
#pragma unroll
    for (int subk = 0; subk < 2; ++subk) {
      bf16x8 af[4], bfr[4];
#pragma unroll
      for (int i = 0; i < 4; ++i)
        af[i] = *(const bf16x8*)&Ac[swz(wr * 64 + i * 16 + lrow, subk * 4 + lq)];
#pragma unroll
      for (int j = 0; j < 4; ++j)
        bfr[j] = *(const bf16x8*)&Bc[swz(wc * 64 + j * 16 + lrow, subk * 4 + lq)];
#pragma unroll
      for (int i = 0; i < 4; ++i)
#pragma unroll
        for (int j = 0; j < 4; ++j)
          acc[i][j] = __builtin_amdgcn_mfma_f32_16x16x32_bf16(af[i], bfr[j], acc[i][j], 0, 0, 0);
    }
    S_LGKM0;
    if (t < 7) { S_VMCNT(0); }
    S_BAR;
  }
#pragma unroll
  for (int i = 0; i < 4; ++i) {
#pragma unroll
    for (int j = 0; j < 4; ++j) {
      const int col = c0 + wc * 64 + j * 16 + lrow;
      const float bv = bias[col];
#pragma unroll
      for (int p = 0; p < 4; ++p) {
        const long row = r0 + wr * 64 + i * 16 + lq * 4 + p;
        Y[row * 512 + col] = acc[i][j][p] + bv;
      }
    }
  }
}

// ---------------------------------------------------------------------------
// weight transpose+convert: W [K,N] fp32 -> blocked swizzled bf16 images for
// the 512x512 GEMM weights (m<4); row-major [N,K] bf16 for W1/W2.
// ---------------------------------------------------------------------------
struct TArgs {
  const float* src[6];
  u16* dst[6];
  int K[6];
  int N[6];
};
__global__ __launch_bounds__(256)
void transpose_w(TArgs a)
{
  const int m = blockIdx.z;
  const int K = a.K[m], N = a.N[m];
  const int kt = blockIdx.y * 64, nt = blockIdx.x * 64;
  if (kt >= K || nt >= N) return;
  const float* src = a.src[m];
  u16* dst = a.dst[m];
  __shared__ u16 t[64][72];
  const int tx = threadIdx.x & 15, ty = threadIdx.x >> 4;
#pragma unroll
  for (int rr = 0; rr < 64; rr += 16) {
    const int k = kt + ty + rr;
    float4 v = *(const float4*)(src + (long)k * N + nt + tx * 4);
    t[tx * 4 + 0][ty + rr] = f2bf(v.x);
    t[tx * 4 + 1][ty + rr] = f2bf(v.y);
    t[tx * 4 + 2][ty + rr] = f2bf(v.z);
    t[tx * 4 + 3][ty + rr] = f2bf(v.w);
  }
  __syncthreads();
  if (m < 4) {
    const int ktile = kt >> 6;
#pragma unroll
    for (int it = 0; it < 2; ++it) {
      const int s = threadIdx.x + it * 256;
      const int r = s >> 3, c = (s & 7) * 8;
      const int n = nt + r;
      const int colblk = n >> 7, cl = n & 127;
      ushort4 u0 = *(ushort4*)&t[r][c];
      ushort4 u1 = *(ushort4*)&t[r][c + 4];
      u16* d = dst + ((long)colblk * 8 + ktile) * 8192 + cl * 64 + (c ^ ((cl & 7) << 3));
      *(ushort4*)d = u0;
      *(ushort4*)(d + 4) = u1;
    }
  } else {
#pragma unroll
    for (int it = 0; it < 2; ++it) {
      const int s = threadIdx.x + it * 256;
      const int r = s >> 3, c = (s & 7) * 8;
      ushort4 u0 = *(ushort4*)&t[r][c];
      ushort4 u1 = *(ushort4*)&t[r][c + 4];
      *(ushort4*)(dst + (long)(nt + r) * K + kt + c) = u0;
      *(ushort4*)(dst + (long)(nt + r) * K + kt + c + 4) = u1;
    }
  }
}

// ---------------------------------------------------------------------------
// kv GEMM: D[d][e] = sum_m kaT*vT, split-K 16, + ksum via ones.
// ---------------------------------------------------------------------------
__global__ __launch_bounds__(256, 2)
void kv_gemm(const u16* __restrict__ kaT, const u16* __restrict__ vT,
             float* __restrict__ kvp, float* __restrict__ ksp)
{
  const int sp = blockIdx.x;
  const int bh = blockIdx.y;
  __shared__ __align__(16) u16 SB[32768];
  const int tid = threadIdx.x, wv = tid >> 6, lane = tid & 63;
  const int lrow = lane & 15, lq = lane >> 4;
  f32x4 acc[4][4] = {};
  f32x4 accs[4] = {};
  bf16x8 ones;
#pragma unroll
  for (int z = 0; z < 8; ++z) ones[z] = (__bf16)1.0f;
  const long base = (long)bh * 64 * 4096;

#pragma unroll
  for (int ph = 0; ph < 2; ++ph) {
    const int m0 = sp * 256 + ph * 128;
#pragma unroll
    for (int i = 0; i < 4; ++i) {
      const int s = (wv * 4 + i) * 64 + lane;
      const int chunk = s >> 8, row = (s >> 2) & 63, part = s & 3;
      const long g = base + (long)row * 4096 + m0 + chunk * 32 + part * 8;
      async16(kaT + g, &SB[ph * 16384 + (wv * 4 + i) * 512]);
      async16(vT + g, &SB[ph * 16384 + 8192 + (wv * 4 + i) * 512]);
    }
    S_FENCE;
  }

#pragma unroll
  for (int ph = 0; ph < 2; ++ph) {
    if (ph == 0) { S_VMCNT(8); } else { S_VMCNT(0); }
    const u16* As = SB + ph * 16384;
    const u16* Bs = As + 8192;
    bf16x8 af[4], bfr[4];
#pragma unroll
    for (int i = 0; i < 4; ++i)
      af[i] = *(const bf16x8*)&As[wv * 2048 + (i * 16 + lrow) * 32 + lq * 8];
#pragma unroll
    for (int j = 0; j < 4; ++j)
      bfr[j] = *(const bf16x8*)&Bs[wv * 2048 + (j * 16 + lrow) * 32 + lq * 8];
#pragma unroll
    for (int i = 0; i < 4; ++i) {
#pragma unroll
      for (int j = 0; j < 4; ++j)
        acc[i][j] = __builtin_amdgcn_mfma_f32_16x16x32_bf16(af[i], bfr[j], acc[i][j], 0, 0, 0);
      accs[i] = __builtin_amdgcn_mfma_f32_16x16x32_bf16(af[i], ones, accs[i], 0, 0, 0);
    }
  }

  float* red = (float*)SB;
  float* ksr = red + 64 * 68;
  for (int w = 0; w < 4; ++w) {
    __syncthreads();
    if (wv == w) {
#pragma unroll
      for (int i = 0; i < 4; ++i) {
#pragma unroll
        for (int j = 0; j < 4; ++j) {
          const int e = j * 16 + lrow, dd = i * 16 + lq * 4;
          float* p = &red[e * 68 + dd];
          if (w == 0) { p[0] = acc[i][j][0]; p[1] = acc[i][j][1]; p[2] = acc[i][j][2]; p[3] = acc[i][j][3]; }
          else        { p[0] += acc[i][j][0]; p[1] += acc[i][j][1]; p[2] += acc[i][j][2]; p[3] += acc[i][j][3]; }
        }
        if (lrow == 0) {
          const int dd = i * 16 + lq * 4;
#pragma unroll
          for (int p2 = 0; p2 < 4; ++p2) {
            if (w == 0) ksr[dd + p2] = accs[i][p2];
            else        ksr[dd + p2] += accs[i][p2];
          }
        }
      }
    }
  }
  __syncthreads();
  float* kvo = kvp + ((long)sp * 32 + bh) * 4096;
  for (int s = tid; s < 4096; s += 256) kvo[s] = red[(s >> 6) * 68 + (s & 63)];
  if (tid < 64) ksp[(sp * 32 + bh) * 64 + tid] = ksr[tid];
}

__global__ __launch_bounds__(256)
void kv_reduce(const float* __restrict__ kvp, const float* __restrict__ ksp,
               u16* __restrict__ kvT, u16* __restrict__ ksumT)
{
  const int bh = blockIdx.x;
  const int t = threadIdx.x;
  const int s0 = blockIdx.y * 512;
#pragma unroll
  for (int i = 0; i < 2; ++i) {
    const int s = s0 + i * 256 + t;
    float v = 0.f;
#pragma unroll
    for (int sp = 0; sp < 16; ++sp) v += kvp[((long)sp * 32 + bh) * 4096 + s];
    kvT[(long)bh * 4096 + s] = f2bf(v);
  }
  if (blockIdx.y == 0 && t < 64) {
    float v = 0.f;
#pragma unroll
    for (int sp = 0; sp < 16; ++sp) v += ksp[(sp * 32 + bh) * 64 + t];
    ksumT[bh * 64 + t] = f2bf(v);
  }
}

// ---------------------------------------------------------------------------
// attn MFMA: out[n][e] = (q@kv) / max(q@ksum,1e-6).
// Output written as blocked swizzled images for out_gemm.
// ---------------------------------------------------------------------------
__global__ __launch_bounds__(256)
void attn_mfma(const u16* __restrict__ q, const u16* __restrict__ kvT,
               const u16* __restrict__ ksumT, u16* __restrict__ attn)
{
  __shared__ u16 SB[17408];
  const int tid = threadIdx.x, wv = tid >> 6, lane = tid & 63;
  const int lrow = lane & 15, lq = lane >> 4;
  const int n0 = blockIdx.x * 256;
  const int bh = blockIdx.y, b = bh >> 3, h = bh & 7;
  u16* As = SB;

#pragma unroll
  for (int half = 0; half < 2; ++half)
#pragma unroll
    for (int i = 0; i < 4; ++i) {
      const int s = (wv * 4 + i) * 64 + lane;
      async16(q + ((long)(b * 4096 + n0 + (s >> 2))) * 512 + h * 64 + half * 32 + (s & 3) * 8,
              &As[half * 8192 + (wv * 4 + i) * 512]);
    }
  bf16x8 bfr[2][4], ks[2];
#pragma unroll
  for (int half = 0; half < 2; ++half) {
#pragma unroll
    for (int j = 0; j < 4; ++j)
      bfr[half][j] = *(const bf16x8*)(kvT + ((long)bh * 64 + j * 16 + lrow) * 64 + half * 32 + lq * 8);
    ks[half] = *(const bf16x8*)(ksumT + bh * 64 + half * 32 + lq * 8);
  }
  __syncthreads();

  f32x4 acc[4][4] = {};
  f32x4 accd[4] = {};
#pragma unroll
  for (int half = 0; half < 2; ++half) {
    bf16x8 af[4];
#pragma unroll
    for (int i = 0; i < 4; ++i)
      af[i] = *(const bf16x8*)&As[half * 8192 + (wv * 64 + i * 16 + lrow) * 32 + lq * 8];
#pragma unroll
    for (int i = 0; i < 4; ++i) {
#pragma unroll
      for (int j = 0; j < 4; ++j)
        acc[i][j] = __builtin_amdgcn_mfma_f32_16x16x32_bf16(af[i], bfr[half][j], acc[i][j], 0, 0, 0);
      accd[i] = __builtin_amdgcn_mfma_f32_16x16x32_bf16(af[i], ks[half], accd[i], 0, 0, 0);
    }
  }
  __syncthreads();

  u16* LT = SB;
#pragma unroll
  for (int i = 0; i < 4; ++i) {
    float dinv[4];
#pragma unroll
    for (int p = 0; p < 4; ++p) dinv[p] = 1.f / fmaxf(accd[i][p], 1e-6f);
#pragma unroll
    for (int j = 0; j < 4; ++j) {
      const int e = j * 16 + lrow;
      const int nl0 = i * 16 + lq * 4;
      ushort4 w;
      float x0 = acc[i][j][0] * dinv[0], x1 = acc[i][j][1] * dinv[1];
      float x2 = acc[i][j][2] * dinv[2], x3 = acc[i][j][3] * dinv[3];
      if (!(x0 == x0)) x0 = 0.f;
      if (!(x1 == x1)) x1 = 0.f;
      if (!(x2 == x2)) x2 = 0.f;
      if (!(x3 == x3)) x3 = 0.f;
      w.x = f2bf(fminf(65000.f, fmaxf(-65000.f, x0)));
      w.y = f2bf(fminf(65000.f, fmaxf(-65000.f, x1)));
      w.z = f2bf(fminf(65000.f, fmaxf(-65000.f, x2)));
      w.w = f2bf(fminf(65000.f, fmaxf(-65000.f, x3)));
      *(ushort4*)&LT[wv * 4352 + e * 68 + nl0] = w;
    }
  }
  __syncthreads();
#pragma unroll
  for (int it = 0; it < 8; ++it) {
    const int c = it * 256 + tid;
    const int n = c & 255, ec = c >> 8;
    const int wr2 = n >> 6, nl = n & 63;
    ushort4 w0, w1;
    w0.x = LT[wr2 * 4352 + (ec * 8 + 0) * 68 + nl];
    w0.y = LT[wr2 * 4352 + (ec * 8 + 1) * 68 + nl];
    w0.z = LT[wr2 * 4352 + (ec * 8 + 2) * 68 + nl];
    w0.w = LT[wr2 * 4352 + (ec * 8 + 3) * 68 + nl];
    w1.x = LT[wr2 * 4352 + (ec * 8 + 4) * 68 + nl];
    w1.y = LT[wr2 * 4352 + (ec * 8 + 5) * 68 + nl];
    w1.z = LT[wr2 * 4352 + (ec * 8 + 6) * 68 + nl];
    w1.w = LT[wr2 * 4352 + (ec * 8 + 7) * 68 + nl];
    const int ng = b * 4096 + n0 + n;
    const int rowblk = ng >> 7, rl = ng & 127;
    u16* dst = attn + ((long)rowblk * 8 + h) * 8192 + rl * 64 + ((ec * 8) ^ ((rl & 7) << 3));
    *(ushort4*)dst = w0;
    *(ushort4*)(dst + 4) = w1;
  }
}

// ---------------------------------------------------------------------------
static constexpr long U = 8388608;   // elems of one [4,4096,512] tensor

extern "C" void kernel_launch(void* const* d_in, const int* in_sizes, int n_in,
                              void* d_out, int out_size, void* d_ws, size_t ws_size,
                              hipStream_t stream)
{
  const float* query = (const float*)d_in[0];
  const float* key   = (const float*)d_in[1];
  const float* value = (const float*)d_in[2];
  const float* Wq = (const float*)d_in[3];
  const float* bq = (const float*)d_in[4];
  const float* Wk = (const float*)d_in[5];
  const float* bk = (const float*)d_in[6];
  const float* Wv = (const float*)d_in[7];
  const float* bv = (const float*)d_in[8];
  const float* W1 = (const float*)d_in[9];
  const float* b1 = (const float*)d_in[10];
  const float* W2 = (const float*)d_in[11];
  const float* b2 = (const float*)d_in[12];
  const float* Wo = (const float*)d_in[13];
  const float* bo = (const float*)d_in[14];

  u16* wsh = (u16*)d_ws;
  u16* qact = wsh;           // [16384,512] bf16
  u16* vT   = wsh + 2 * U;   // vT[b][h][e][m]
  u16* kaT  = wsh + 3 * U;   // [32][64][4096]
  u16* attn = wsh + 4 * U;   // blocked swizzled [128 rowblk][8 ktile][8192]

  float* fp  = (float*)(wsh + 5 * U);
  float* kvp = fp;                     // 16*32*4096
  float* ksp = fp + 2097152;           // 16*32*64
  u16* kvTg   = (u16*)(fp + 2129920);  // 32*4096
  u16* ksumTg = kvTg + 131072;         // 32*64
  u16* wtb = ksumTg + 2048;
  u16* WqT = wtb;                      // blocked [4][8][8192]
  u16* WkT = wtb + 262144;
  u16* WvT = wtb + 524288;
  u16* WoT = wtb + 786432;
  u16* W1T = wtb + 1048576;            // [128,64] row-major
  u16* W2T = wtb + 1056768;            // [64,128] row-major

  dim3 blk(256);
  const float invM = 1.f / 4096.f;

  TArgs ta;
  ta.src[0] = Wq; ta.dst[0] = WqT; ta.K[0] = 512; ta.N[0] = 512;
  ta.src[1] = Wk; ta.dst[1] = WkT; ta.K[1] = 512; ta.N[1] = 512;
  ta.src[2] = Wv; ta.dst[2] = WvT; ta.K[2] = 512; ta.N[2] = 512;
  ta.src[3] = Wo; ta.dst[3] = WoT; ta.K[3] = 512; ta.N[3] = 512;
  ta.src[4] = W1; ta.dst[4] = W1T; ta.K[4] = 64;  ta.N[4] = 128;
  ta.src[5] = W2; ta.dst[5] = W2T; ta.K[5] = 128; ta.N[5] = 64;
  transpose_w<<<dim3(8, 8, 6), blk, 0, stream>>>(ta);

  // fused q/k/v projections + per-head MLP on the k path (writes kaT directly)
  qkv_gemm<<<dim3(128, 4, 3), blk, 0, stream>>>(query, key, value, WqT, WkT, WvT,
                                                bq, bk, bv, W1T, W2T, b1, b2,
                                                qact, vT, kaT, invM);
  // kv context + ksum (MFMA split-K 16) then reduce to bf16
  kv_gemm<<<dim3(16, 32), blk, 0, stream>>>(kaT, vT, kvp, ksp);
  kv_reduce<<<dim3(32, 8), blk, 0, stream>>>(kvp, ksp, kvTg, ksumTg);
  // attention output (blocked swizzled layout for out_gemm)
  attn_mfma<<<dim3(16, 32), blk, 0, stream>>>(qact, kvTg, ksumTg, attn);
  // final projection -> d_out fp32
  out_gemm<<<dim3(128, 4), blk, 0, stream>>>(attn, WoT, bo, (float*)d_out);
}